// Round 13
// baseline (150.884 us; speedup 1.0000x reference)
//
#include <hip/hip_runtime.h>

#define BB 128
#define NN 8192
#define SS 100
#define KK 512
#define NT 512                 // 8 waves -> up to 4 blocks/CU at VGPR<=64
#define EPT 16                 // elements per thread (one sample per block)
#define CAND 256
#define NBIN 2048
#define NWAVE 8

#define GIDX(e) (((e) >> 2) * 2048 + tid * 4 + ((e) & 3))
#define LN2 0.69314718056f

// LDS-only barrier: waits DS ops but leaves global loads in flight
// (__syncthreads drains vmcnt(0) too — guide §5). sched_barrier stops the
// compiler hoisting LDS reads above the wait (guide rule #18).
__device__ __forceinline__ void lds_barrier() {
    asm volatile("s_waitcnt lgkmcnt(0)" ::: "memory");
    __builtin_amdgcn_s_barrier();
    __builtin_amdgcn_sched_barrier(0);
}

// Deterministic fast p: bit-identical at every callsite.
__device__ __forceinline__ float p_of(float u, float lgv) {
    const float g1 = __builtin_amdgcn_logf(u + 1e-20f);   // log2(u+eps)
    const float w  = fmaf(g1, -LN2, 1e-20f);              // -ln(u+eps)+eps
    const float g2 = __builtin_amdgcn_logf(w);            // log2(w)
    return fmaf(g2, -LN2, lgv);                           // lg - ln(w)
}

// Monotone linear bin map [-12,24] -> [0,2047]; covers this op's p range
// (~[-8.4, 21.3]); clamped edge bins stay exact via in-bin tie ranking.
#define SCB (2048.0f / 36.0f)
#define OFB (12.0f * SCB)
__device__ __forceinline__ int bin_of(float p) {
    int b = (int)fmaf(p, SCB, OFB);
    b = b < 0 ? 0 : b;
    return b > 2047 ? 2047 : b;
}

// One block = one (b,s) sample row. 5 LDS barriers; global loads are never
// drained by a barrier. R9 algorithm at half-block granularity.
// MODE 0: write 16-bit membership bitmap per thread to ws. MODE 1: atomicAdd.
template <int MODE>
__global__ __launch_bounds__(NT) void gumbel_topk_kernel(
    const float* __restrict__ logits,
    const float* __restrict__ uniform,
    unsigned short* __restrict__ ws,
    float* __restrict__ out) {

    __shared__ __align__(16) int hist[NBIN];
    __shared__ float ck[CAND];
    __shared__ int   ci[CAND];
    __shared__ int   waveTot[NWAVE];
    __shared__ int   bsel, bkk, cnt;

    const int tid  = threadIdx.x;
    const int lane = tid & 63;
    const int wv   = tid >> 6;
    const int b    = blockIdx.x / SS;

    const float* lrow = logits + (size_t)b * NN;
    const float* urow = uniform + (size_t)blockIdx.x * NN;  // == (b*SS+s)*NN

    // ---- issue ALL global loads upfront; they stay in flight across s0
    float p[EPT], lg[EPT];
#pragma unroll
    for (int j = 0; j < 4; ++j) {
        *reinterpret_cast<float4*>(&p[j * 4]) =
            *reinterpret_cast<const float4*>(&urow[j * 2048 + tid * 4]);
        *reinterpret_cast<float4*>(&lg[j * 4]) =
            *reinterpret_cast<const float4*>(&lrow[j * 2048 + tid * 4]);
    }

    // ---- init LDS: 2048 ints over 512 threads = one int4 each
    *reinterpret_cast<int4*>(&hist[tid * 4]) = make_int4(0, 0, 0, 0);
    if (tid == 0) cnt = 0;
    lds_barrier();                                        // s0

    // ---- transform + histogram (lg dies here; p stays live)
#pragma unroll
    for (int e = 0; e < EPT; ++e) {
        p[e] = p_of(p[e], lg[e]);
        atomicAdd(&hist[bin_of(p[e])], 1);
    }
    lds_barrier();                                        // s1

    // ---- cross-wave suffix scan (4 bins/thread), locate threshold bin
    const int base = tid * 4;
    const int4 h = *reinterpret_cast<const int4*>(&hist[base]);
    const int sum = h.x + h.y + h.z + h.w;
    int suf = sum;
#pragma unroll
    for (int d = 1; d < 64; d <<= 1) {
        const int o = __shfl_down(suf, d);
        if (lane + d < 64) suf += o;
    }
    if (lane == 0) waveTot[wv] = suf;
    lds_barrier();                                        // s2

    int cum = suf - sum;                  // strictly higher bins' count
    for (int w2 = wv + 1; w2 < NWAVE; ++w2) cum += waveTot[w2];
    if (cum < KK && cum + h.w >= KK) { bsel = base + 3; bkk = KK - cum; }
    cum += h.w;
    if (cum < KK && cum + h.z >= KK) { bsel = base + 2; bkk = KK - cum; }
    cum += h.z;
    if (cum < KK && cum + h.y >= KK) { bsel = base + 1; bkk = KK - cum; }
    cum += h.y;
    if (cum < KK && cum + h.x >= KK) { bsel = base + 0; bkk = KK - cum; }
    lds_barrier();                                        // s3

    const int sel = bsel, kk = bkk;

    // ---- collect threshold-bin candidates (~5 expected; keys from live p)
#pragma unroll
    for (int e = 0; e < EPT; ++e) {
        if (bin_of(p[e]) == sel) {
            const int pos = atomicAdd(&cnt, 1);
            if (pos < CAND) { ck[pos] = p[e]; ci[pos] = GIDX(e); }
        }
    }
    lds_barrier();                                        // s4

    // ---- membership bit per element; in-bin elements rank themselves
    // (key desc, index asc = JAX tie-break)
    const int c = cnt < CAND ? cnt : CAND;
    unsigned bits = 0;
#pragma unroll
    for (int e = 0; e < EPT; ++e) {
        const int bb = bin_of(p[e]);
        if (bb > sel) {
            bits |= 1u << e;
        } else if (bb == sel) {
            const float kl = p[e]; const int il = GIDX(e);
            int r = 0;
            for (int j = 0; j < c; ++j)
                r += (ck[j] > kl || (ck[j] == kl && ci[j] < il)) ? 1 : 0;
            if (r < kk) bits |= 1u << e;
        }
    }

    if (MODE == 0) {
        ws[(size_t)blockIdx.x * NT + tid] = (unsigned short)bits;
    } else {
        float* orow = out + (size_t)b * NN;
#pragma unroll
        for (int e = 0; e < EPT; ++e)
            if ((bits >> e) & 1u) atomicAdd(orow + GIDX(e), 0.01f);
    }
}

// Sum 100 membership bitmaps per (b, thread-slot); bit e of slot t maps to
// out[b][(e>>2)*2048 + t*4 + (e&3)]. Coalesced u16 reads across lanes.
__global__ __launch_bounds__(256) void reduce_kernel(
    const unsigned short* __restrict__ ws, float* __restrict__ out) {
    const int g = blockIdx.x * 256 + threadIdx.x;   // 0..65535
    const int b = g >> 9;
    const int t = g & 511;
    const unsigned short* base = ws + (size_t)b * SS * NT + t;
    int acc[EPT];
#pragma unroll
    for (int e = 0; e < EPT; ++e) acc[e] = 0;
    for (int s = 0; s < SS; ++s) {
        const unsigned w = base[(size_t)s * NT];
#pragma unroll
        for (int e = 0; e < EPT; ++e) acc[e] += (w >> e) & 1u;
    }
    float* ob = out + (size_t)b * NN;
#pragma unroll
    for (int q = 0; q < 4; ++q) {
        const float4 o = make_float4(acc[q * 4 + 0] * 0.01f, acc[q * 4 + 1] * 0.01f,
                                     acc[q * 4 + 2] * 0.01f, acc[q * 4 + 3] * 0.01f);
        *reinterpret_cast<float4*>(&ob[q * 2048 + t * 4]) = o;
    }
}

extern "C" void kernel_launch(void* const* d_in, const int* in_sizes, int n_in,
                              void* d_out, int out_size, void* d_ws, size_t ws_size,
                              hipStream_t stream) {
    const float* logits  = (const float*)d_in[0];   // [128, 8192] f32
    const float* uniform = (const float*)d_in[1];   // [128, 100, 8192] f32
    float* out = (float*)d_out;                     // [128, 8192] f32

    const int grid = BB * SS;                       // 12800 blocks, 1/sample
    const size_t need = (size_t)grid * NT * sizeof(unsigned short);  // 13.1 MB

    if (ws_size >= need) {
        gumbel_topk_kernel<0><<<grid, NT, 0, stream>>>(
            logits, uniform, (unsigned short*)d_ws, nullptr);
        reduce_kernel<<<(BB * NT) / 256, 256, 0, stream>>>(
            (const unsigned short*)d_ws, out);
    } else {
        hipMemsetAsync(out, 0, (size_t)out_size * sizeof(float), stream);
        gumbel_topk_kernel<1><<<grid, NT, 0, stream>>>(
            logits, uniform, nullptr, out);
    }
}

// Round 14
// 111.696 us; speedup vs baseline: 1.3508x; 1.3508x over previous
//
#include <hip/hip_runtime.h>

#define BB 128
#define NN 8192
#define SS 100
#define KK 512
#define SPLIT 50               // sample PAIRS per batch row (SPB=2)
#define NT 1024                // 16 waves
#define EPT 8                  // elements per thread per sample
#define CAND 256
#define NBIN 2048
#define NWAVE 16

#define GIDX(e) (((e) >> 2) * 4096 + tid * 4 + ((e) & 3))
#define LN2 0.69314718056f

// LDS-only barrier: waits DS ops but leaves global loads in flight
// (__syncthreads drains vmcnt(0) too — guide §5). sched_barrier stops the
// compiler hoisting LDS reads above the wait (guide rule #18).
__device__ __forceinline__ void lds_barrier() {
    asm volatile("s_waitcnt lgkmcnt(0)" ::: "memory");
    __builtin_amdgcn_s_barrier();
    __builtin_amdgcn_sched_barrier(0);
}

// q-key: q = (-ln(u+eps)+eps) * e^{-lg} = e^{-p} (monotone DECREASING in p).
// ONE transcendental per element-sample; e^{-lg} is precomputed per logit.
__device__ __forceinline__ float q_of(float u, float elg) {
    const float w = fmaf(__builtin_amdgcn_logf(u + 1e-20f), -LN2, 1e-20f);
    return w * elg;
}

// Monotone bin map via float bits: bits(q)>>16 = sign(0)|exp(8)|mant(7),
// monotone in q. Flip so HIGHER bin = HIGHER p. Window covers
// q in [2^-13, 16) i.e. p in (-2.77, 9]; outside clamps, and clamped bins
// stay exact via the in-bin rank loop (exact q compares).
__device__ __forceinline__ int bin_of(float q) {
    const int t = (int)(__float_as_uint(q) >> 16);
    int b = 16639 - t;
    b = b < 0 ? 0 : b;
    return b > 2047 ? 2047 : b;
}

// elg[i] = e^{-logits[i]} (one v_exp per logit, reused over 100 samples)
__global__ __launch_bounds__(256) void exp_kernel(
    const float* __restrict__ logits, float* __restrict__ elg) {
    const int i = blockIdx.x * 256 + threadIdx.x;
    const float4 v = reinterpret_cast<const float4*>(logits)[i];
    float4 o;
    o.x = __expf(-v.x); o.y = __expf(-v.y);
    o.z = __expf(-v.z); o.w = __expf(-v.w);
    reinterpret_cast<float4*>(elg)[i] = o;
}

// One block = (b, pair of samples). 5 LDS barriers; global loads are never
// drained by a barrier. R9 structure with the q-space key (1 log/elem).
// MODE 0: counts->ws. MODE 1: atomicAdd out (computes elg inline from logits).
template <int MODE>
__global__ __launch_bounds__(NT, 8) void gumbel_topk_kernel(
    const float* __restrict__ elg_or_logits,
    const float* __restrict__ uniform,
    unsigned short* __restrict__ ws,
    float* __restrict__ out) {

    __shared__ __align__(16) int histA[NBIN];
    __shared__ __align__(16) int histB[NBIN];
    __shared__ float ckA[CAND];
    __shared__ int   ciA[CAND];
    __shared__ float ckB[CAND];
    __shared__ int   ciB[CAND];
    __shared__ int waveTotA[NWAVE], waveTotB[NWAVE];
    __shared__ int bselA, bkkA, bselB, bkkB, cntA, cntB;

    const int tid  = threadIdx.x;
    const int lane = tid & 63;
    const int wv   = tid >> 6;
    const int b    = blockIdx.x / SPLIT;
    const int ch   = blockIdx.x % SPLIT;

    const float* erow  = elg_or_logits + (size_t)b * NN;
    const float* uArow = uniform + ((size_t)b * SS + ch * 2) * NN;
    const float* uBrow = uArow + NN;

    // ---- issue ALL global loads upfront; they stay in flight across s0
    float le[EPT], qA[EPT], qB[EPT];
#pragma unroll
    for (int j = 0; j < 2; ++j) {
        *reinterpret_cast<float4*>(&qA[j * 4]) =
            *reinterpret_cast<const float4*>(&uArow[j * 4096 + tid * 4]);
        *reinterpret_cast<float4*>(&qB[j * 4]) =
            *reinterpret_cast<const float4*>(&uBrow[j * 4096 + tid * 4]);
        *reinterpret_cast<float4*>(&le[j * 4]) =
            *reinterpret_cast<const float4*>(&erow[j * 4096 + tid * 4]);
    }
    if (MODE == 1) {            // inline elg when no precompute buffer
#pragma unroll
        for (int e = 0; e < EPT; ++e) le[e] = __expf(-le[e]);
    }

    // ---- init LDS: 4096 ints over 1024 threads = one int4 each
    if (tid < 512) *reinterpret_cast<int4*>(&histA[tid * 4]) = make_int4(0, 0, 0, 0);
    else           *reinterpret_cast<int4*>(&histB[(tid - 512) * 4]) = make_int4(0, 0, 0, 0);
    if (tid == 0) { cntA = 0; cntB = 0; }
    lds_barrier();                                        // s0

    // ---- transform (1 log/elem) + histogram; q stays live in registers
#pragma unroll
    for (int e = 0; e < EPT; ++e) {
        qA[e] = q_of(qA[e], le[e]);
        qB[e] = q_of(qB[e], le[e]);
        atomicAdd(&histA[bin_of(qA[e])], 1);
        atomicAdd(&histB[bin_of(qB[e])], 1);
    }
    lds_barrier();                                        // s1

    // ---- cross-wave suffix scan of both hists (2 bins/thread); the
    // crossing thread broadcasts (sel, kk). 2 barriers.
    {
        const int base = tid * 2;
        const int2 hA = *reinterpret_cast<const int2*>(&histA[base]);
        const int2 hB = *reinterpret_cast<const int2*>(&histB[base]);
        const int sumA = hA.x + hA.y, sumB = hB.x + hB.y;
        int sufA = sumA, sufB = sumB;
#pragma unroll
        for (int d = 1; d < 64; d <<= 1) {
            const int oA = __shfl_down(sufA, d);
            const int oB = __shfl_down(sufB, d);
            if (lane + d < 64) { sufA += oA; sufB += oB; }
        }
        if (lane == 0) { waveTotA[wv] = sufA; waveTotB[wv] = sufB; }
        lds_barrier();                                    // s2
        int cumA = sufA - sumA, cumB = sufB - sumB;
        for (int w2 = wv + 1; w2 < NWAVE; ++w2) { cumA += waveTotA[w2]; cumB += waveTotB[w2]; }
        if (cumA < KK && cumA + hA.y >= KK) { bselA = base + 1; bkkA = KK - cumA; }
        cumA += hA.y;
        if (cumA < KK && cumA + hA.x >= KK) { bselA = base;     bkkA = KK - cumA; }
        if (cumB < KK && cumB + hB.y >= KK) { bselB = base + 1; bkkB = KK - cumB; }
        cumB += hB.y;
        if (cumB < KK && cumB + hB.x >= KK) { bselB = base;     bkkB = KK - cumB; }
        lds_barrier();                                    // s3
    }

    const int selA = bselA, kkA = bkkA;
    const int selB = bselB, kkB = bkkB;

    // ---- collect threshold-bin candidates (~3/sample; keys from live q)
#pragma unroll
    for (int e = 0; e < EPT; ++e) {
        if (bin_of(qA[e]) == selA) {
            const int pos = atomicAdd(&cntA, 1);
            if (pos < CAND) { ckA[pos] = qA[e]; ciA[pos] = GIDX(e); }
        }
        if (bin_of(qB[e]) == selB) {
            const int pos = atomicAdd(&cntB, 1);
            if (pos < CAND) { ckB[pos] = qB[e]; ciB[pos] = GIDX(e); }
        }
    }
    lds_barrier();                                        // s4

    // ---- membership: 2-bit count per element; in-bin elements rank by
    // (q asc = p desc, idx asc) — JAX tie-break.
    const int cA = cntA < CAND ? cntA : CAND;
    const int cB = cntB < CAND ? cntB : CAND;
    unsigned cnt8 = 0;
#pragma unroll
    for (int e = 0; e < EPT; ++e) {
        {
            const int bb = bin_of(qA[e]);
            if (bb > selA) {
                cnt8 += 1u << (2 * e);
            } else if (bb == selA) {
                const float kl = qA[e]; const int il = GIDX(e);
                int r = 0;
                for (int j = 0; j < cA; ++j)
                    r += (ckA[j] < kl || (ckA[j] == kl && ciA[j] < il)) ? 1 : 0;
                if (r < kkA) cnt8 += 1u << (2 * e);
            }
        }
        {
            const int bb = bin_of(qB[e]);
            if (bb > selB) {
                cnt8 += 1u << (2 * e);
            } else if (bb == selB) {
                const float kl = qB[e]; const int il = GIDX(e);
                int r = 0;
                for (int j = 0; j < cB; ++j)
                    r += (ckB[j] < kl || (ckB[j] == kl && ciB[j] < il)) ? 1 : 0;
                if (r < kkB) cnt8 += 1u << (2 * e);
            }
        }
    }

    if (MODE == 0) {
        ws[(size_t)blockIdx.x * NT + tid] = (unsigned short)cnt8;
    } else {
        float* orow = out + (size_t)b * NN;
#pragma unroll
        for (int e = 0; e < EPT; ++e) {
            const unsigned c = (cnt8 >> (2 * e)) & 3u;
            if (c) atomicAdd(orow + GIDX(e), (float)c * 0.01f);
        }
    }
}

// Sum 50 packed-2-bit partials per u16 position; each field <= 2, sum <= 100.
__global__ __launch_bounds__(256) void reduce_kernel(
    const unsigned short* __restrict__ ws, float* __restrict__ out) {
    const int g   = blockIdx.x * 256 + threadIdx.x;   // 0..131071
    const int b   = g >> 10;
    const int pos = g & 1023;
    int acc[8] = {0, 0, 0, 0, 0, 0, 0, 0};
    for (int ch = 0; ch < SPLIT; ++ch) {
        const unsigned w = ws[((size_t)(b * SPLIT + ch) << 10) + pos];
#pragma unroll
        for (int e = 0; e < 8; ++e) acc[e] += (w >> (2 * e)) & 3u;
    }
    float* ob = out + (size_t)b * NN;
    const float4 o0 = make_float4(acc[0] * 0.01f, acc[1] * 0.01f,
                                  acc[2] * 0.01f, acc[3] * 0.01f);
    const float4 o1 = make_float4(acc[4] * 0.01f, acc[5] * 0.01f,
                                  acc[6] * 0.01f, acc[7] * 0.01f);
    *reinterpret_cast<float4*>(&ob[pos * 4])        = o0;
    *reinterpret_cast<float4*>(&ob[4096 + pos * 4]) = o1;
}

extern "C" void kernel_launch(void* const* d_in, const int* in_sizes, int n_in,
                              void* d_out, int out_size, void* d_ws, size_t ws_size,
                              hipStream_t stream) {
    const float* logits  = (const float*)d_in[0];   // [128, 8192] f32
    const float* uniform = (const float*)d_in[1];   // [128, 100, 8192] f32
    float* out = (float*)d_out;                     // [128, 8192] f32

    const int grid = BB * SPLIT;                    // 6400 blocks
    const size_t elgBytes = (size_t)BB * NN * sizeof(float);           // 4 MB
    const size_t cntBytes = (size_t)grid * NT * sizeof(unsigned short);// 13 MB

    if (ws_size >= elgBytes + cntBytes) {
        float* elg = (float*)d_ws;
        unsigned short* cnts = (unsigned short*)((char*)d_ws + elgBytes);
        exp_kernel<<<(BB * NN / 4) / 256, 256, 0, stream>>>(logits, elg);
        gumbel_topk_kernel<0><<<grid, NT, 0, stream>>>(
            elg, uniform, cnts, nullptr);
        reduce_kernel<<<(BB * NN / 8) / 256, 256, 0, stream>>>(cnts, out);
    } else {
        hipMemsetAsync(out, 0, (size_t)out_size * sizeof(float), stream);
        gumbel_topk_kernel<1><<<grid, NT, 0, stream>>>(
            logits, uniform, nullptr, out);
    }
}